// Round 8
// baseline (367.681 us; speedup 1.0000x reference)
//
#include <hip/hip_runtime.h>

#define NN 30000
#define NE 480000
#define BN_EPS 1e-5f
#define EBLK 1875     // NE/256 edge blocks
#define FBLK 7500     // fused blocks: 4 nodes each (256 thr = 4 waves, wave/node)
#define PKBLK 469     // ceil(NN*4/256)
#define NSHARD 16     // stats atomic shards

typedef __attribute__((ext_vector_type(8))) short bf16x8;
typedef __attribute__((ext_vector_type(4))) float f32x4;

// ---------------------------------------------------------------------------
// bf16 helpers (RNE pack, cheap unpack)
// ---------------------------------------------------------------------------
__device__ __forceinline__ unsigned short f2bf(float x) {
    unsigned int u = __float_as_uint(x);
    return (unsigned short)((u + 0x7fffu + ((u >> 16) & 1u)) >> 16);
}
__device__ __forceinline__ float bf2f(unsigned short h) {
    return __uint_as_float(((unsigned int)h) << 16);
}

// int64-vs-int32 detect: odd 32-bit words of int64 indices < 2^31 are all 0.
__device__ __forceinline__ int detect64(const unsigned int* __restrict__ ei) {
    unsigned int v = ei[1] | ei[3] | ei[5] | ei[7] |
                     ei[9] | ei[11] | ei[13] | ei[15];
    return v == 0u;
}
__device__ __forceinline__ int load_idx(const void* ei, int is64, int pos) {
    if (is64) return (int)((const long long*)ei)[pos];
    return ((const int*)ei)[pos];
}

// ---------------------------------------------------------------------------
// prep: x -> xbf (bf16), zero degi+cursor+stats shards, pack W0..W2 into MFMA
// B-fragment order (bf16, R5-verified):
//   wb[layer][((ot*8 + kb)*64 + lane)*8 + e] = bf16( W[(m*64+o)*64+kk] )
//   k = kb*32 + (lane>>4)*8 + e,  o = ot*16 + (lane&15),  m=k>>6, kk=k&63.
// ---------------------------------------------------------------------------
__global__ __launch_bounds__(256) void k_prep(const float* __restrict__ x,
                                              const float* __restrict__ W0,
                                              const float* __restrict__ W1,
                                              const float* __restrict__ W2,
                                              ushort* __restrict__ xbf,
                                              int4* __restrict__ zerobase,
                                              ushort* __restrict__ wb) {
    int t = blockIdx.x * 256 + threadIdx.x;
    if (t < 480000) {  // NN*64/4 ushort4s
        float4 v = reinterpret_cast<const float4*>(x)[t];
        ushort4 o;
        o.x = f2bf(v.x); o.y = f2bf(v.y); o.z = f2bf(v.z); o.w = f2bf(v.w);
        reinterpret_cast<ushort4*>(xbf)[t] = o;
    } else if (t < 480000 + 16024) {  // (2*NN ints + 2*NSHARD*128 floats)/4
        zerobase[t - 480000] = make_int4(0, 0, 0, 0);
    } else if (t < 480000 + 16024 + 49152) {
        int t2 = t - (480000 + 16024);
        int layer = t2 >> 14;
        int r = t2 & 16383;
        int ot = r >> 12;
        int kb = (r >> 9) & 7;
        int l = (r >> 3) & 63;
        int e = r & 7;
        int k = kb * 32 + (l >> 4) * 8 + e;
        int o = ot * 16 + (l & 15);
        int m = k >> 6;
        int kk = k & 63;
        const float* W = (layer == 0) ? W0 : (layer == 1) ? W1 : W2;
        wb[t2] = f2bf(W[(m * 64 + o) * 64 + kk]);
    }
}

// ---------------------------------------------------------------------------
// hist: dst-degree histogram (exactly NE threads)
// ---------------------------------------------------------------------------
__global__ __launch_bounds__(256) void k_hist(const void* __restrict__ ei,
                                              int* __restrict__ degi) {
    int e = blockIdx.x * 256 + threadIdx.x;
    int is64 = detect64((const unsigned int*)ei);
    int d = load_idx(ei, is64, NE + e);
    atomicAdd(&degi[d], 1);
}

// ---------------------------------------------------------------------------
// scan: ONE block, 1024 threads, 30 elems/thread -> exclusive rowptr.
// ---------------------------------------------------------------------------
__global__ __launch_bounds__(1024) void k_scan(const int* __restrict__ degi,
                                               int* __restrict__ rowptr) {
    __shared__ int sm[1024];
    const int PER = 30;
    int t = threadIdx.x;
    int base = t * PER;
    int loc[PER];
    int sum = 0;
#pragma unroll
    for (int i = 0; i < PER; ++i) {
        int idx = base + i;
        int d = (idx < NN) ? degi[idx] : 0;
        loc[i] = sum;
        sum += d;
    }
    sm[t] = sum;
    __syncthreads();
    for (int off = 1; off < 1024; off <<= 1) {
        int add = (t >= off) ? sm[t - off] : 0;
        __syncthreads();
        sm[t] += add;
        __syncthreads();
    }
    int tb = sm[t] - sum;
#pragma unroll
    for (int i = 0; i < PER; ++i) {
        int idx = base + i;
        if (idx < NN) rowptr[idx] = tb + loc[i];
    }
    if (t == 0) rowptr[NN] = NE;
}

// ---------------------------------------------------------------------------
// p0 (layer 0, no fold): p[n][m] = x[n,:] @ U0[m,:]
// ---------------------------------------------------------------------------
__device__ __forceinline__ void dev_pk0(const float* __restrict__ h,
                                        const float* __restrict__ U,
                                        float* __restrict__ pout, int vb) {
    __shared__ float usc_s[4][64];
    int t = threadIdx.x;
    {
        int m = t >> 6, k = t & 63;
        usc_s[m][k] = U[m * 64 + k];
    }
    __syncthreads();
    int idx = vb * 256 + t;
    if (idx < NN * 4) {
        int n = idx >> 2, m = idx & 3;
        const float4* hn = reinterpret_cast<const float4*>(h) + (size_t)n * 16;
        const float* um = usc_s[m];
        float a = 0.0f;
#pragma unroll
        for (int j = 0; j < 16; ++j) {
            float4 hv = hn[j];
            a += hv.x * um[4 * j + 0] + hv.y * um[4 * j + 1] +
                 hv.z * um[4 * j + 2] + hv.w * um[4 * j + 3];
        }
        pout[idx] = a;
    }
}

// ---------------------------------------------------------------------------
// Fused: blocks 0..1874 scatter CSR; blocks 1875.. compute p0 = x@U0^T.
// ---------------------------------------------------------------------------
__global__ __launch_bounds__(256) void k_scatter_pk0(const void* __restrict__ ei,
                                                     const int* __restrict__ rowptr,
                                                     int* __restrict__ cursor,
                                                     int* __restrict__ csr,
                                                     const float* __restrict__ x,
                                                     const float* __restrict__ U0,
                                                     float* __restrict__ p) {
    if (blockIdx.x < EBLK) {
        int is64 = detect64((const unsigned int*)ei);
        int e = blockIdx.x * 256 + threadIdx.x;
        int s = load_idx(ei, is64, e);
        int d = load_idx(ei, is64, NE + e);
        int pos = rowptr[d] + atomicAdd(&cursor[d], 1);
        csr[pos] = s;
    } else {
        dev_pk0(x, U0, p, blockIdx.x - EBLK);
    }
}

// ---------------------------------------------------------------------------
// k_pk (fold layers): sums stats shards -> sc/sh; writes scv (block 0),
// cstv (block 0), and p[n][m] = h[n,:] @ (U[m,:]*sc).
// ---------------------------------------------------------------------------
__global__ __launch_bounds__(256) void k_pk(const float* __restrict__ h,
                                            const float* __restrict__ U,
                                            const float* __restrict__ statsS,
                                            const float* __restrict__ g,
                                            const float* __restrict__ W,
                                            const float* __restrict__ bt,
                                            float* __restrict__ pout,
                                            float* __restrict__ cstv_out,
                                            float* __restrict__ scv_out) {
    __shared__ float usc_s[4][64];
    __shared__ float sc_l[64];
    __shared__ float sh_l[64];
    int t = threadIdx.x;
    if (t < 64) {
        float s1 = 0.0f, s2 = 0.0f;
#pragma unroll
        for (int sh = 0; sh < NSHARD; ++sh) {
            s1 += statsS[sh * 128 + t];
            s2 += statsS[sh * 128 + 64 + t];
        }
        const float invN = 1.0f / (float)NN;
        float mu = s1 * invN;
        float var = s2 * invN - mu * mu;
        float sc = rsqrtf(var + BN_EPS) * g[t];
        sc_l[t] = sc;
        sh_l[t] = bt[t] - mu * sc;
        if (blockIdx.x == 0) scv_out[t] = sc;
    }
    __syncthreads();
    {
        int m = t >> 6, k = t & 63;
        usc_s[m][k] = U[m * 64 + k] * sc_l[k];
    }
    __syncthreads();
    int idx = blockIdx.x * 256 + t;
    if (idx < NN * 4) {
        int n = idx >> 2, m = idx & 3;
        const float4* hn = reinterpret_cast<const float4*>(h) + (size_t)n * 16;
        const float* um = usc_s[m];
        float a = 0.0f;
#pragma unroll
        for (int j = 0; j < 16; ++j) {
            float4 hv = hn[j];
            a += hv.x * um[4 * j + 0] + hv.y * um[4 * j + 1] +
                 hv.z * um[4 * j + 2] + hv.w * um[4 * j + 3];
        }
        pout[idx] = a;
    }
    if (blockIdx.x == 0) {
        float s = 0.0f;
        const float* wr = W + (size_t)t * 64;
#pragma unroll 8
        for (int k = 0; k < 64; ++k) s += sh_l[k] * wr[k];
        cstv_out[t] = s;
    }
}

// ---------------------------------------------------------------------------
// BARRIER-FREE fused aggregate + GEMM. 256 thr = 4 waves = 4 nodes/block.
// Each wave: (A) gather-aggregate its node, write bf16 z row to its PRIVATE
// LDS slice (same-wave RAW -> compiler-inserted lgkmcnt, no barrier);
// (B) read A-frags with ALL 16 rows = this z row (k = kb*32+(l>>4)*8+e),
// so all D rows are identical and lane l holds out[n][l] as acc_{l>>4}[0].
// 16x redundant MFMA rows are free (matrix pipe ~idle). Stats via 16-shard
// global atomics (no block reduction -> no barrier).
// __launch_bounds__(256,4): 128-VGPR cap — relaxed from R7's (256,6)/85-VGPR,
// the only code-level suspect for the R7 container failure.
// ---------------------------------------------------------------------------
template <int FOLD, int STATS>
__global__ __launch_bounds__(256, 4) void k_fused(const int* __restrict__ rowptr,
                                                  const int* __restrict__ csr,
                                                  const float* __restrict__ p,
                                                  const ushort* __restrict__ hbf_in,
                                                  const float* __restrict__ cvec,
                                                  const float* __restrict__ scv,
                                                  const float* __restrict__ cstv,
                                                  const ushort* __restrict__ wb,
                                                  const float* __restrict__ bvec,
                                                  float* __restrict__ hout,
                                                  ushort* __restrict__ hbfout,
                                                  float* __restrict__ stats_out) {
    __shared__ float4 attn_s[4][64];
    __shared__ int src_s[4][64];
    __shared__ ushort zrow[4][272];   // 544B stride (16B-aligned), wave-private

    int t = threadIdx.x;
    int wid = t >> 6;
    int lane = t & 63;
    int n = blockIdx.x * 4 + wid;
    const float4* p4 = reinterpret_cast<const float4*>(p);

    float scl = FOLD ? scv[lane] : 1.0f;

    float4 cv = make_float4(cvec[0], cvec[1], cvec[2], cvec[3]);
    float smx = fmaxf(fmaxf(cv.x, cv.y), fmaxf(cv.z, cv.w));
    float se0 = __expf(cv.x - smx), se1 = __expf(cv.y - smx);
    float se2 = __expf(cv.z - smx), se3 = __expf(cv.w - smx);
    float sinv = 1.0f / (se0 + se1 + se2 + se3);
    float sl0 = se0 * sinv, sl1 = se1 * sinv, sl2 = se2 * sinv, sl3 = se3 * sinv;

    float4 pd = p4[n];
    float4 pdc = make_float4(pd.x + cv.x, pd.y + cv.y, pd.z + cv.z, pd.w + cv.w);
    float hs = bf2f(hbf_in[(unsigned)(n * 64 + lane)]);
    float acc0 = sl0 * hs, acc1 = sl1 * hs, acc2 = sl2 * hs, acc3 = sl3 * hs;
    float zt0 = sl0, zt1 = sl1, zt2 = sl2, zt3 = sl3;

    int start = rowptr[n];
    int end = rowptr[n + 1];
    for (int j = start; j < end; j += 64) {
        int chunk = end - j;
        if (chunk > 64) chunk = 64;
        if (lane < chunk) {
            int s = csr[j + lane];
            float4 q = p4[(unsigned)s];
            float l0 = pdc.x - q.x;
            float l1 = pdc.y - q.y;
            float l2 = pdc.z - q.z;
            float l3 = pdc.w - q.w;
            float mx = fmaxf(fmaxf(l0, l1), fmaxf(l2, l3));  // REQUIRED (R5 NaN)
            float e0 = __expf(l0 - mx);
            float e1 = __expf(l1 - mx);
            float e2 = __expf(l2 - mx);
            float e3 = __expf(l3 - mx);
            float inv = 1.0f / (e0 + e1 + e2 + e3);
            attn_s[wid][lane] = make_float4(e0 * inv, e1 * inv, e2 * inv, e3 * inv);
            src_s[wid][lane] = s;
        }
        int k = 0;
        for (; k + 4 <= chunk; k += 4) {
            float4 a0 = attn_s[wid][k];
            int s0 = src_s[wid][k];
            float4 a1 = attn_s[wid][k + 1];
            int s1 = src_s[wid][k + 1];
            float4 a2 = attn_s[wid][k + 2];
            int s2 = src_s[wid][k + 2];
            float4 a3 = attn_s[wid][k + 3];
            int s3 = src_s[wid][k + 3];
            float h0 = bf2f(hbf_in[(unsigned)(s0 * 64 + lane)]);
            float h1 = bf2f(hbf_in[(unsigned)(s1 * 64 + lane)]);
            float h2 = bf2f(hbf_in[(unsigned)(s2 * 64 + lane)]);
            float h3 = bf2f(hbf_in[(unsigned)(s3 * 64 + lane)]);
            acc0 += a0.x * h0 + a1.x * h1 + a2.x * h2 + a3.x * h3;
            acc1 += a0.y * h0 + a1.y * h1 + a2.y * h2 + a3.y * h3;
            acc2 += a0.z * h0 + a1.z * h1 + a2.z * h2 + a3.z * h3;
            acc3 += a0.w * h0 + a1.w * h1 + a2.w * h2 + a3.w * h3;
            zt0 += a0.x + a1.x + a2.x + a3.x;
            zt1 += a0.y + a1.y + a2.y + a3.y;
            zt2 += a0.z + a1.z + a2.z + a3.z;
            zt3 += a0.w + a1.w + a2.w + a3.w;
        }
        for (; k < chunk; ++k) {
            float4 a0 = attn_s[wid][k];
            int s0 = src_s[wid][k];
            float h0 = bf2f(hbf_in[(unsigned)(s0 * 64 + lane)]);
            acc0 += a0.x * h0;
            acc1 += a0.y * h0;
            acc2 += a0.z * h0;
            acc3 += a0.w * h0;
            zt0 += a0.x; zt1 += a0.y; zt2 += a0.z; zt3 += a0.w;
        }
    }

    float invD = 1.0f / (float)(end - start + 1);
    float s = invD * scl;
    ushort* zr = &zrow[wid][0];
    zr[lane]       = f2bf(acc0 * s);
    zr[64 + lane]  = f2bf(acc1 * s);
    zr[128 + lane] = f2bf(acc2 * s);
    zr[192 + lane] = f2bf(acc3 * s);
    // same-wave LDS RAW: compiler orders via lgkmcnt; no __syncthreads anywhere

    // ---- phase B (per-wave): replicated-row MFMA, K=256 ----
    int grp = lane >> 4;
    f32x4 ac0 = {0.0f, 0.0f, 0.0f, 0.0f};
    f32x4 ac1 = {0.0f, 0.0f, 0.0f, 0.0f};
    f32x4 ac2 = {0.0f, 0.0f, 0.0f, 0.0f};
    f32x4 ac3 = {0.0f, 0.0f, 0.0f, 0.0f};
#pragma unroll
    for (int kb = 0; kb < 8; ++kb) {
        bf16x8 a = *reinterpret_cast<const bf16x8*>(zr + kb * 32 + grp * 8);
        const ushort* wk = wb + (size_t)(kb * 64 + lane) * 8;
        bf16x8 b0 = *reinterpret_cast<const bf16x8*>(wk);
        bf16x8 b1 = *reinterpret_cast<const bf16x8*>(wk + 4096);
        bf16x8 b2 = *reinterpret_cast<const bf16x8*>(wk + 8192);
        bf16x8 b3 = *reinterpret_cast<const bf16x8*>(wk + 12288);
        ac0 = __builtin_amdgcn_mfma_f32_16x16x32_bf16(a, b0, ac0, 0, 0, 0);
        ac1 = __builtin_amdgcn_mfma_f32_16x16x32_bf16(a, b1, ac1, 0, 0, 0);
        ac2 = __builtin_amdgcn_mfma_f32_16x16x32_bf16(a, b2, ac2, 0, 0, 0);
        ac3 = __builtin_amdgcn_mfma_f32_16x16x32_bf16(a, b3, ac3, 0, 0, 0);
    }
    // lane l wants col (l&15) of o-tile (l>>4): all acc rows identical -> [0]
    float v = (grp == 0) ? ac0[0] : (grp == 1) ? ac1[0]
            : (grp == 2) ? ac2[0] : ac3[0];

    if (FOLD) {
        v += (zt0 * cstv[lane] + zt1 * cstv[64 + lane] +
              zt2 * cstv[128 + lane] + zt3 * cstv[192 + lane]) * invD;
    }
    v += bvec[lane];

    if (STATS) {
        v = fmaxf(v, 0.0f);
        hout[(size_t)n * 64 + lane] = v;
        hbfout[(size_t)n * 64 + lane] = f2bf(v);
        float* so = stats_out + (blockIdx.x & (NSHARD - 1)) * 128;
        atomicAdd(&so[lane], v);
        atomicAdd(&so[64 + lane], v * v);
    } else {
        hout[(size_t)n * 64 + lane] = v;
    }
}

extern "C" void kernel_launch(void* const* d_in, const int* in_sizes, int n_in,
                              void* d_out, int out_size, void* d_ws, size_t ws_size,
                              hipStream_t stream) {
    const float* x = (const float*)d_in[0];
    const void* ei = d_in[1];
    const float* W0 = (const float*)d_in[2];
    const float* U0 = (const float*)d_in[3];
    const float* c0 = (const float*)d_in[4];
    const float* b0 = (const float*)d_in[5];
    const float* g0 = (const float*)d_in[6];
    const float* bt0 = (const float*)d_in[7];
    const float* W1 = (const float*)d_in[8];
    const float* U1 = (const float*)d_in[9];
    const float* c1 = (const float*)d_in[10];
    const float* b1 = (const float*)d_in[11];
    const float* g1 = (const float*)d_in[12];
    const float* bt1 = (const float*)d_in[13];
    const float* W2 = (const float*)d_in[14];
    const float* U2 = (const float*)d_in[15];
    const float* c2 = (const float*)d_in[16];
    const float* b2 = (const float*)d_in[17];

    // workspace layout — all 16B-aligned
    ushort* xbf = (ushort*)d_ws;                      // NN*64 bf16
    ushort* hbfA = xbf + (size_t)NN * 64;             // NN*64 (double buffer A)
    ushort* hbfB = hbfA + (size_t)NN * 64;            // NN*64 (double buffer B)
    float* h = (float*)(hbfB + (size_t)NN * 64);      // NN*64 fp32
    float* p = h + (size_t)NN * 64;                   // NN*4
    float* cstv = p + (size_t)NN * 4;                 // 256
    float* scv = cstv + 256;                          // 64
    int* degi = (int*)(scv + 64);                     // NN   } zeroed as one
    int* cursor = degi + NN;                          // NN   } int4 region
    float* statsA = (float*)(cursor + NN);            // 2*16*128 = 4096
    int* rowptr = (int*)(statsA + 4096);              // NN+4
    int* csr = rowptr + NN + 4;                       // NE
    ushort* wb = (ushort*)(csr + NE);                 // 3*16384 bf16
    float* stats0 = statsA;
    float* stats1 = statsA + 2048;

    const int prepBlocks = (480000 + 16024 + 49152 + 255) / 256;  // 2130

    // 9 dispatches
    k_prep<<<prepBlocks, 256, 0, stream>>>(x, W0, W1, W2, xbf, (int4*)degi, wb);
    k_hist<<<EBLK, 256, 0, stream>>>(ei, degi);
    k_scan<<<1, 1024, 0, stream>>>(degi, rowptr);
    k_scatter_pk0<<<EBLK + PKBLK, 256, 0, stream>>>(ei, rowptr, cursor, csr,
                                                    x, U0, p);

    // ---- layer 0: read xbf, write h + hbfA, stats0 shards ----
    k_fused<0, 1><<<FBLK, 256, 0, stream>>>(rowptr, csr, p, xbf, c0,
                                            nullptr, nullptr, wb, b0,
                                            h, hbfA, stats0);
    // ---- layer 1: fold BN0; read hbfA, write h + hbfB, stats1 shards ----
    k_pk<<<PKBLK, 256, 0, stream>>>(h, U1, stats0, g0, W1, bt0, p, cstv, scv);
    k_fused<1, 1><<<FBLK, 256, 0, stream>>>(rowptr, csr, p, hbfA, c1,
                                            scv, cstv, wb + 16384, b1,
                                            h, hbfB, stats1);
    // ---- layer 2: fold BN1; read hbfB, write d_out ----
    k_pk<<<PKBLK, 256, 0, stream>>>(h, U2, stats1, g1, W2, bt1, p, cstv, scv);
    k_fused<1, 0><<<FBLK, 256, 0, stream>>>(rowptr, csr, p, hbfB, c2,
                                            scv, cstv, wb + 32768, b2,
                                            (float*)d_out, nullptr, nullptr);
}

// Round 9
// 260.888 us; speedup vs baseline: 1.4093x; 1.4093x over previous
//
#include <hip/hip_runtime.h>

#define NN 30000
#define NE 480000
#define BN_EPS 1e-5f
#define EBLK 1875     // NE/256 edge blocks
#define FBLK 3750     // fused blocks: 8 nodes each (512 thr = 8 waves, wave/node)
#define PKBLK 469     // ceil(NN*4/256)
#define NSHARD 16     // stats atomic shards

typedef __attribute__((ext_vector_type(8))) short bf16x8;
typedef __attribute__((ext_vector_type(4))) float f32x4;

// ---------------------------------------------------------------------------
// bf16 helpers (RNE pack, cheap unpack)
// ---------------------------------------------------------------------------
__device__ __forceinline__ unsigned short f2bf(float x) {
    unsigned int u = __float_as_uint(x);
    return (unsigned short)((u + 0x7fffu + ((u >> 16) & 1u)) >> 16);
}
__device__ __forceinline__ float bf2f(unsigned short h) {
    return __uint_as_float(((unsigned int)h) << 16);
}

// int64-vs-int32 detect: odd 32-bit words of int64 indices < 2^31 are all 0.
__device__ __forceinline__ int detect64(const unsigned int* __restrict__ ei) {
    unsigned int v = ei[1] | ei[3] | ei[5] | ei[7] |
                     ei[9] | ei[11] | ei[13] | ei[15];
    return v == 0u;
}
__device__ __forceinline__ int load_idx(const void* ei, int is64, int pos) {
    if (is64) return (int)((const long long*)ei)[pos];
    return ((const int*)ei)[pos];
}

// ---------------------------------------------------------------------------
// prep: x -> xbf (bf16), zero degi+cursor+stats shards, pack W0..W2 into MFMA
// B-fragment order (bf16, R5-verified):
//   wb[layer][((ot*8 + kb)*64 + lane)*8 + e] = bf16( W[(m*64+o)*64+kk] )
//   k = kb*32 + (lane>>4)*8 + e,  o = ot*16 + (lane&15),  m=k>>6, kk=k&63.
// ---------------------------------------------------------------------------
__global__ __launch_bounds__(256) void k_prep(const float* __restrict__ x,
                                              const float* __restrict__ W0,
                                              const float* __restrict__ W1,
                                              const float* __restrict__ W2,
                                              ushort* __restrict__ xbf,
                                              int4* __restrict__ zerobase,
                                              ushort* __restrict__ wb) {
    int t = blockIdx.x * 256 + threadIdx.x;
    if (t < 480000) {  // NN*64/4 ushort4s
        float4 v = reinterpret_cast<const float4*>(x)[t];
        ushort4 o;
        o.x = f2bf(v.x); o.y = f2bf(v.y); o.z = f2bf(v.z); o.w = f2bf(v.w);
        reinterpret_cast<ushort4*>(xbf)[t] = o;
    } else if (t < 480000 + 16024) {  // (2*NN ints + 2*NSHARD*128 floats)/4
        zerobase[t - 480000] = make_int4(0, 0, 0, 0);
    } else if (t < 480000 + 16024 + 49152) {
        int t2 = t - (480000 + 16024);
        int layer = t2 >> 14;
        int r = t2 & 16383;
        int ot = r >> 12;
        int kb = (r >> 9) & 7;
        int l = (r >> 3) & 63;
        int e = r & 7;
        int k = kb * 32 + (l >> 4) * 8 + e;
        int o = ot * 16 + (l & 15);
        int m = k >> 6;
        int kk = k & 63;
        const float* W = (layer == 0) ? W0 : (layer == 1) ? W1 : W2;
        wb[t2] = f2bf(W[(m * 64 + o) * 64 + kk]);
    }
}

// ---------------------------------------------------------------------------
// hist: dst-degree histogram (exactly NE threads)
// ---------------------------------------------------------------------------
__global__ __launch_bounds__(256) void k_hist(const void* __restrict__ ei,
                                              int* __restrict__ degi) {
    int e = blockIdx.x * 256 + threadIdx.x;
    int is64 = detect64((const unsigned int*)ei);
    int d = load_idx(ei, is64, NE + e);
    atomicAdd(&degi[d], 1);
}

// ---------------------------------------------------------------------------
// scan: ONE block, 1024 threads, 30 elems/thread -> exclusive rowptr.
// ---------------------------------------------------------------------------
__global__ __launch_bounds__(1024) void k_scan(const int* __restrict__ degi,
                                               int* __restrict__ rowptr) {
    __shared__ int sm[1024];
    const int PER = 30;
    int t = threadIdx.x;
    int base = t * PER;
    int loc[PER];
    int sum = 0;
#pragma unroll
    for (int i = 0; i < PER; ++i) {
        int idx = base + i;
        int d = (idx < NN) ? degi[idx] : 0;
        loc[i] = sum;
        sum += d;
    }
    sm[t] = sum;
    __syncthreads();
    for (int off = 1; off < 1024; off <<= 1) {
        int add = (t >= off) ? sm[t - off] : 0;
        __syncthreads();
        sm[t] += add;
        __syncthreads();
    }
    int tb = sm[t] - sum;
#pragma unroll
    for (int i = 0; i < PER; ++i) {
        int idx = base + i;
        if (idx < NN) rowptr[idx] = tb + loc[i];
    }
    if (t == 0) rowptr[NN] = NE;
}

// ---------------------------------------------------------------------------
// p0 (layer 0, no fold): p[n][m] = x[n,:] @ U0[m,:]
// ---------------------------------------------------------------------------
__device__ __forceinline__ void dev_pk0(const float* __restrict__ h,
                                        const float* __restrict__ U,
                                        float* __restrict__ pout, int vb) {
    __shared__ float usc_s[4][64];
    int t = threadIdx.x;
    {
        int m = t >> 6, k = t & 63;
        usc_s[m][k] = U[m * 64 + k];
    }
    __syncthreads();
    int idx = vb * 256 + t;
    if (idx < NN * 4) {
        int n = idx >> 2, m = idx & 3;
        const float4* hn = reinterpret_cast<const float4*>(h) + (size_t)n * 16;
        const float* um = usc_s[m];
        float a = 0.0f;
#pragma unroll
        for (int j = 0; j < 16; ++j) {
            float4 hv = hn[j];
            a += hv.x * um[4 * j + 0] + hv.y * um[4 * j + 1] +
                 hv.z * um[4 * j + 2] + hv.w * um[4 * j + 3];
        }
        pout[idx] = a;
    }
}

// ---------------------------------------------------------------------------
// Fused: blocks 0..1874 scatter CSR; blocks 1875.. compute p0 = x@U0^T.
// ---------------------------------------------------------------------------
__global__ __launch_bounds__(256) void k_scatter_pk0(const void* __restrict__ ei,
                                                     const int* __restrict__ rowptr,
                                                     int* __restrict__ cursor,
                                                     int* __restrict__ csr,
                                                     const float* __restrict__ x,
                                                     const float* __restrict__ U0,
                                                     float* __restrict__ p) {
    if (blockIdx.x < EBLK) {
        int is64 = detect64((const unsigned int*)ei);
        int e = blockIdx.x * 256 + threadIdx.x;
        int s = load_idx(ei, is64, e);
        int d = load_idx(ei, is64, NE + e);
        int pos = rowptr[d] + atomicAdd(&cursor[d], 1);
        csr[pos] = s;
    } else {
        dev_pk0(x, U0, p, blockIdx.x - EBLK);
    }
}

// ---------------------------------------------------------------------------
// k_pk (fold layers): sums stats shards -> sc/sh; writes scv (block 0),
// cstv (block 0), and p[n][m] = h[n,:] @ (U[m,:]*sc).
// ---------------------------------------------------------------------------
__global__ __launch_bounds__(256) void k_pk(const float* __restrict__ h,
                                            const float* __restrict__ U,
                                            const float* __restrict__ statsS,
                                            const float* __restrict__ g,
                                            const float* __restrict__ W,
                                            const float* __restrict__ bt,
                                            float* __restrict__ pout,
                                            float* __restrict__ cstv_out,
                                            float* __restrict__ scv_out) {
    __shared__ float usc_s[4][64];
    __shared__ float sc_l[64];
    __shared__ float sh_l[64];
    int t = threadIdx.x;
    if (t < 64) {
        float s1 = 0.0f, s2 = 0.0f;
#pragma unroll
        for (int sh = 0; sh < NSHARD; ++sh) {
            s1 += statsS[sh * 128 + t];
            s2 += statsS[sh * 128 + 64 + t];
        }
        const float invN = 1.0f / (float)NN;
        float mu = s1 * invN;
        float var = s2 * invN - mu * mu;
        float sc = rsqrtf(var + BN_EPS) * g[t];
        sc_l[t] = sc;
        sh_l[t] = bt[t] - mu * sc;
        if (blockIdx.x == 0) scv_out[t] = sc;
    }
    __syncthreads();
    {
        int m = t >> 6, k = t & 63;
        usc_s[m][k] = U[m * 64 + k] * sc_l[k];
    }
    __syncthreads();
    int idx = blockIdx.x * 256 + t;
    if (idx < NN * 4) {
        int n = idx >> 2, m = idx & 3;
        const float4* hn = reinterpret_cast<const float4*>(h) + (size_t)n * 16;
        const float* um = usc_s[m];
        float a = 0.0f;
#pragma unroll
        for (int j = 0; j < 16; ++j) {
            float4 hv = hn[j];
            a += hv.x * um[4 * j + 0] + hv.y * um[4 * j + 1] +
                 hv.z * um[4 * j + 2] + hv.w * um[4 * j + 3];
        }
        pout[idx] = a;
    }
    if (blockIdx.x == 0) {
        float s = 0.0f;
        const float* wr = W + (size_t)t * 64;
#pragma unroll 8
        for (int k = 0; k < 64; ++k) s += sh_l[k] * wr[k];
        cstv_out[t] = s;
    }
}

// ---------------------------------------------------------------------------
// Fused aggregate + GEMM, 8-wave gang. 512 thr = 8 waves = 8 nodes/block,
// 4 gangs/CU (vs R6's 2 with 1024-thr blocks). Phase A: wave per node,
// lane = channel; gather-aggregate, scale by invD*sc, write bf16 z row to
// LDS + zs. ONE barrier. Phase B: waves 0..3 take one 16-col o-tile each
// over the 8 nodes (MFMA A rows 8..15 clamped, outputs discarded); waves
// 4..7 exit (no later barrier -> safe). Weight traffic 4 KB/node (vs 32 KB
// in R8's barrier-free version - its downfall). Stats: grp-fold shuffle +
// lane<16 atomics into 16 shards.
// ---------------------------------------------------------------------------
template <int FOLD, int STATS>
__global__ __launch_bounds__(512, 4) void k_fused(const int* __restrict__ rowptr,
                                                  const int* __restrict__ csr,
                                                  const float* __restrict__ p,
                                                  const ushort* __restrict__ hbf_in,
                                                  const float* __restrict__ cvec,
                                                  const float* __restrict__ scv,
                                                  const float* __restrict__ cstvg,
                                                  const ushort* __restrict__ wb,
                                                  const float* __restrict__ bvec,
                                                  float* __restrict__ hout,
                                                  ushort* __restrict__ hbfout,
                                                  float* __restrict__ stats_out) {
    __shared__ float4 attn_s[8][64];
    __shared__ int src_s[8][64];
    __shared__ ushort zrow[8][272];   // 544B stride: 16B-aligned rows
    __shared__ float4 zs_s[8];
    __shared__ float cstv_s[256];

    int t = threadIdx.x;
    int wid = t >> 6;
    int lane = t & 63;
    int n = blockIdx.x * 8 + wid;
    const float4* p4 = reinterpret_cast<const float4*>(p);

    if (FOLD && t < 256) cstv_s[t] = cstvg[t];

    float scl = FOLD ? scv[lane] : 1.0f;

    float4 cv = make_float4(cvec[0], cvec[1], cvec[2], cvec[3]);
    float smx = fmaxf(fmaxf(cv.x, cv.y), fmaxf(cv.z, cv.w));
    float se0 = __expf(cv.x - smx), se1 = __expf(cv.y - smx);
    float se2 = __expf(cv.z - smx), se3 = __expf(cv.w - smx);
    float sinv = 1.0f / (se0 + se1 + se2 + se3);
    float sl0 = se0 * sinv, sl1 = se1 * sinv, sl2 = se2 * sinv, sl3 = se3 * sinv;

    float4 pd = p4[n];
    float4 pdc = make_float4(pd.x + cv.x, pd.y + cv.y, pd.z + cv.z, pd.w + cv.w);
    float hs = bf2f(hbf_in[(unsigned)(n * 64 + lane)]);
    float acc0 = sl0 * hs, acc1 = sl1 * hs, acc2 = sl2 * hs, acc3 = sl3 * hs;
    float zt0 = sl0, zt1 = sl1, zt2 = sl2, zt3 = sl3;

    int start = rowptr[n];
    int end = rowptr[n + 1];
    for (int j = start; j < end; j += 64) {
        int chunk = end - j;
        if (chunk > 64) chunk = 64;
        if (lane < chunk) {
            int s = csr[j + lane];
            float4 q = p4[(unsigned)s];
            float l0 = pdc.x - q.x;
            float l1 = pdc.y - q.y;
            float l2 = pdc.z - q.z;
            float l3 = pdc.w - q.w;
            float mx = fmaxf(fmaxf(l0, l1), fmaxf(l2, l3));  // REQUIRED (R5 NaN)
            float e0 = __expf(l0 - mx);
            float e1 = __expf(l1 - mx);
            float e2 = __expf(l2 - mx);
            float e3 = __expf(l3 - mx);
            float inv = 1.0f / (e0 + e1 + e2 + e3);
            attn_s[wid][lane] = make_float4(e0 * inv, e1 * inv, e2 * inv, e3 * inv);
            src_s[wid][lane] = s;
        }
        int k = 0;
        for (; k + 4 <= chunk; k += 4) {
            float4 a0 = attn_s[wid][k];
            int s0 = src_s[wid][k];
            float4 a1 = attn_s[wid][k + 1];
            int s1 = src_s[wid][k + 1];
            float4 a2 = attn_s[wid][k + 2];
            int s2 = src_s[wid][k + 2];
            float4 a3 = attn_s[wid][k + 3];
            int s3 = src_s[wid][k + 3];
            float h0 = bf2f(hbf_in[(unsigned)(s0 * 64 + lane)]);
            float h1 = bf2f(hbf_in[(unsigned)(s1 * 64 + lane)]);
            float h2 = bf2f(hbf_in[(unsigned)(s2 * 64 + lane)]);
            float h3 = bf2f(hbf_in[(unsigned)(s3 * 64 + lane)]);
            acc0 += a0.x * h0 + a1.x * h1 + a2.x * h2 + a3.x * h3;
            acc1 += a0.y * h0 + a1.y * h1 + a2.y * h2 + a3.y * h3;
            acc2 += a0.z * h0 + a1.z * h1 + a2.z * h2 + a3.z * h3;
            acc3 += a0.w * h0 + a1.w * h1 + a2.w * h2 + a3.w * h3;
            zt0 += a0.x + a1.x + a2.x + a3.x;
            zt1 += a0.y + a1.y + a2.y + a3.y;
            zt2 += a0.z + a1.z + a2.z + a3.z;
            zt3 += a0.w + a1.w + a2.w + a3.w;
        }
        for (; k < chunk; ++k) {
            float4 a0 = attn_s[wid][k];
            int s0 = src_s[wid][k];
            float h0 = bf2f(hbf_in[(unsigned)(s0 * 64 + lane)]);
            acc0 += a0.x * h0;
            acc1 += a0.y * h0;
            acc2 += a0.z * h0;
            acc3 += a0.w * h0;
            zt0 += a0.x; zt1 += a0.y; zt2 += a0.z; zt3 += a0.w;
        }
    }

    float invD = 1.0f / (float)(end - start + 1);
    float s = invD * scl;
    {
        ushort* zr = &zrow[wid][0];
        zr[lane]       = f2bf(acc0 * s);
        zr[64 + lane]  = f2bf(acc1 * s);
        zr[128 + lane] = f2bf(acc2 * s);
        zr[192 + lane] = f2bf(acc3 * s);
        if (lane == 0)
            zs_s[wid] = make_float4(zt0 * invD, zt1 * invD, zt2 * invD, zt3 * invD);
    }
    __syncthreads();

    // ---- phase B: waves 0..3, one o-tile each; waves 4..7 done ----
    if (wid >= 4) return;

    int col = lane & 15;
    int grp = lane >> 4;
    int r = (col < 8) ? col : 7;        // A rows 8..15 clamped (discarded)
    const ushort* zr = &zrow[r][0];
    const ushort* wbp = wb + ((size_t)(wid * 8) * 64 + lane) * 8;
    f32x4 acc = {0.0f, 0.0f, 0.0f, 0.0f};
#pragma unroll
    for (int kb = 0; kb < 8; ++kb) {
        bf16x8 a = *reinterpret_cast<const bf16x8*>(zr + kb * 32 + grp * 8);
        bf16x8 b = *reinterpret_cast<const bf16x8*>(wbp + (size_t)kb * 512);
        acc = __builtin_amdgcn_mfma_f32_16x16x32_bf16(a, b, acc, 0, 0, 0);
    }

    // D layout: row=(lane>>4)*4+i, col=lane&15. Valid rows 0..7 -> grp<2.
    float ls = 0.0f, lq = 0.0f;
    if (grp < 2) {
        int n0 = blockIdx.x * 8;
        int o = wid * 16 + col;
        float bval = bvec[o];
#pragma unroll
        for (int i = 0; i < 4; ++i) {
            int nn = n0 + grp * 4 + i;
            float v = acc[i] + bval;
            if (FOLD) {
                float4 zv = zs_s[grp * 4 + i];
                v += zv.x * cstv_s[o] + zv.y * cstv_s[64 + o] +
                     zv.z * cstv_s[128 + o] + zv.w * cstv_s[192 + o];
            }
            if (STATS) {
                v = fmaxf(v, 0.0f);
                hout[(size_t)nn * 64 + o] = v;
                hbfout[(size_t)nn * 64 + o] = f2bf(v);
                ls += v;
                lq += v * v;
            } else {
                hout[(size_t)nn * 64 + o] = v;
            }
        }
        if (STATS) {
            // fold grp1 (rows 4..7) into grp0 (rows 0..3): lanes 0..31 active
            ls += __shfl_xor(ls, 16, 64);
            lq += __shfl_xor(lq, 16, 64);
            if (lane < 16) {
                float* so = stats_out + (blockIdx.x & (NSHARD - 1)) * 128;
                atomicAdd(&so[o], ls);
                atomicAdd(&so[64 + o], lq);
            }
        }
    }
}

extern "C" void kernel_launch(void* const* d_in, const int* in_sizes, int n_in,
                              void* d_out, int out_size, void* d_ws, size_t ws_size,
                              hipStream_t stream) {
    const float* x = (const float*)d_in[0];
    const void* ei = d_in[1];
    const float* W0 = (const float*)d_in[2];
    const float* U0 = (const float*)d_in[3];
    const float* c0 = (const float*)d_in[4];
    const float* b0 = (const float*)d_in[5];
    const float* g0 = (const float*)d_in[6];
    const float* bt0 = (const float*)d_in[7];
    const float* W1 = (const float*)d_in[8];
    const float* U1 = (const float*)d_in[9];
    const float* c1 = (const float*)d_in[10];
    const float* b1 = (const float*)d_in[11];
    const float* g1 = (const float*)d_in[12];
    const float* bt1 = (const float*)d_in[13];
    const float* W2 = (const float*)d_in[14];
    const float* U2 = (const float*)d_in[15];
    const float* c2 = (const float*)d_in[16];
    const float* b2 = (const float*)d_in[17];

    // workspace layout — all 16B-aligned
    ushort* xbf = (ushort*)d_ws;                      // NN*64 bf16
    ushort* hbfA = xbf + (size_t)NN * 64;             // NN*64 (double buffer A)
    ushort* hbfB = hbfA + (size_t)NN * 64;            // NN*64 (double buffer B)
    float* h = (float*)(hbfB + (size_t)NN * 64);      // NN*64 fp32
    float* p = h + (size_t)NN * 64;                   // NN*4
    float* cstv = p + (size_t)NN * 4;                 // 256
    float* scv = cstv + 256;                          // 64
    int* degi = (int*)(scv + 64);                     // NN   } zeroed as one
    int* cursor = degi + NN;                          // NN   } int4 region
    float* statsA = (float*)(cursor + NN);            // 2*16*128 = 4096
    int* rowptr = (int*)(statsA + 4096);              // NN+4
    int* csr = rowptr + NN + 4;                       // NE
    ushort* wb = (ushort*)(csr + NE);                 // 3*16384 bf16
    float* stats0 = statsA;
    float* stats1 = statsA + 2048;

    const int prepBlocks = (480000 + 16024 + 49152 + 255) / 256;  // 2130

    // 9 dispatches
    k_prep<<<prepBlocks, 256, 0, stream>>>(x, W0, W1, W2, xbf, (int4*)degi, wb);
    k_hist<<<EBLK, 256, 0, stream>>>(ei, degi);
    k_scan<<<1, 1024, 0, stream>>>(degi, rowptr);
    k_scatter_pk0<<<EBLK + PKBLK, 256, 0, stream>>>(ei, rowptr, cursor, csr,
                                                    x, U0, p);

    // ---- layer 0: read xbf, write h + hbfA, stats0 shards ----
    k_fused<0, 1><<<FBLK, 512, 0, stream>>>(rowptr, csr, p, xbf, c0,
                                            nullptr, nullptr, wb, b0,
                                            h, hbfA, stats0);
    // ---- layer 1: fold BN0; read hbfA, write h + hbfB, stats1 shards ----
    k_pk<<<PKBLK, 256, 0, stream>>>(h, U1, stats0, g0, W1, bt0, p, cstv, scv);
    k_fused<1, 1><<<FBLK, 512, 0, stream>>>(rowptr, csr, p, hbfA, c1,
                                            scv, cstv, wb + 16384, b1,
                                            h, hbfB, stats1);
    // ---- layer 2: fold BN1; read hbfB, write d_out ----
    k_pk<<<PKBLK, 256, 0, stream>>>(h, U2, stats1, g1, W2, bt1, p, cstv, scv);
    k_fused<1, 0><<<FBLK, 512, 0, stream>>>(rowptr, csr, p, hbfB, c2,
                                            scv, cstv, wb + 32768, b2,
                                            (float*)d_out, nullptr, nullptr);
}

// Round 10
// 257.650 us; speedup vs baseline: 1.4271x; 1.0126x over previous
//
#include <hip/hip_runtime.h>

#define NN 30000
#define NE 480000
#define BN_EPS 1e-5f
#define EBLK 1875     // NE/256 edge blocks
#define FBLK 3750     // fused blocks: 8 nodes each (512 thr = 8 waves, wave/node)
#define PKBLK 469     // ceil(NN*4/256)
#define NSHARD 16     // stats atomic shards

typedef __attribute__((ext_vector_type(8))) short bf16x8;
typedef __attribute__((ext_vector_type(4))) float f32x4;

// ---------------------------------------------------------------------------
// bf16 helpers (RNE pack, cheap unpack)
// ---------------------------------------------------------------------------
__device__ __forceinline__ unsigned short f2bf(float x) {
    unsigned int u = __float_as_uint(x);
    return (unsigned short)((u + 0x7fffu + ((u >> 16) & 1u)) >> 16);
}
__device__ __forceinline__ float bf2f(unsigned short h) {
    return __uint_as_float(((unsigned int)h) << 16);
}

// int64-vs-int32 detect: odd 32-bit words of int64 indices < 2^31 are all 0.
__device__ __forceinline__ int detect64(const unsigned int* __restrict__ ei) {
    unsigned int v = ei[1] | ei[3] | ei[5] | ei[7] |
                     ei[9] | ei[11] | ei[13] | ei[15];
    return v == 0u;
}
__device__ __forceinline__ int load_idx(const void* ei, int is64, int pos) {
    if (is64) return (int)((const long long*)ei)[pos];
    return ((const int*)ei)[pos];
}

// ---------------------------------------------------------------------------
// prep ∥ hist (one dispatch; disjoint outputs; degi pre-zeroed by memset):
//   blocks [0,1875):    x -> xbf (bf16)
//   blocks [1875,2067): pack W0..W2 into MFMA B-fragment order (R5-verified):
//     wb[layer][((ot*8+kb)*64+lane)*8+e] = bf16(W[(m*64+o)*64+kk]),
//     k = kb*32+(lane>>4)*8+e, o = ot*16+(lane&15), m=k>>6, kk=k&63.
//   blocks [2067,2071): zero stats shards (4096 floats)
//   blocks [2071,3946): dst-degree histogram
// ---------------------------------------------------------------------------
__global__ __launch_bounds__(256) void k_prep_hist(const float* __restrict__ x,
                                                   const float* __restrict__ W0,
                                                   const float* __restrict__ W1,
                                                   const float* __restrict__ W2,
                                                   const void* __restrict__ ei,
                                                   ushort* __restrict__ xbf,
                                                   ushort* __restrict__ wb,
                                                   int4* __restrict__ statz,
                                                   int* __restrict__ degi) {
    int b = blockIdx.x;
    int tid = threadIdx.x;
    if (b < 1875) {
        int t = b * 256 + tid;  // < 480000 = NN*64/4
        float4 v = reinterpret_cast<const float4*>(x)[t];
        ushort4 o;
        o.x = f2bf(v.x); o.y = f2bf(v.y); o.z = f2bf(v.z); o.w = f2bf(v.w);
        reinterpret_cast<ushort4*>(xbf)[t] = o;
    } else if (b < 2067) {
        int t2 = (b - 1875) * 256 + tid;  // < 49152
        int layer = t2 >> 14;
        int r = t2 & 16383;
        int ot = r >> 12;
        int kb = (r >> 9) & 7;
        int l = (r >> 3) & 63;
        int e = r & 7;
        int k = kb * 32 + (l >> 4) * 8 + e;
        int o = ot * 16 + (l & 15);
        int m = k >> 6;
        int kk = k & 63;
        const float* W = (layer == 0) ? W0 : (layer == 1) ? W1 : W2;
        wb[t2] = f2bf(W[(m * 64 + o) * 64 + kk]);
    } else if (b < 2071) {
        statz[(b - 2067) * 256 + tid] = make_int4(0, 0, 0, 0);  // 1024 int4
    } else {
        int e = (b - 2071) * 256 + tid;  // < NE
        int is64 = detect64((const unsigned int*)ei);
        int d = load_idx(ei, is64, NE + e);
        atomicAdd(&degi[d], 1);
    }
}

// ---------------------------------------------------------------------------
// scan: ONE block, 1024 threads. Coalesced grid-stride load of degi into
// 120 KB LDS (fixes the stride-120B uncoalesced per-thread pattern), then
// thread-local exclusive prefix (30/thread) + block scan -> rowptr.
// ---------------------------------------------------------------------------
__global__ __launch_bounds__(1024) void k_scan(const int* __restrict__ degi,
                                               int* __restrict__ rowptr) {
    __shared__ int buf[30720];   // 120 KB (gfx950: 160 KB/CU, single block)
    __shared__ int sm[1024];
    int t = threadIdx.x;
    for (int i = t; i < 30720; i += 1024)
        buf[i] = (i < NN) ? degi[i] : 0;
    __syncthreads();
    const int PER = 30;
    int base = t * PER;
    int loc[PER];
    int sum = 0;
#pragma unroll
    for (int i = 0; i < PER; ++i) {  // LDS stride-30: 2-way bank alias (free)
        loc[i] = sum;
        sum += buf[base + i];
    }
    sm[t] = sum;
    __syncthreads();
    for (int off = 1; off < 1024; off <<= 1) {
        int add = (t >= off) ? sm[t - off] : 0;
        __syncthreads();
        sm[t] += add;
        __syncthreads();
    }
    int tb = sm[t] - sum;
#pragma unroll
    for (int i = 0; i < PER; ++i) {
        int idx = base + i;
        if (idx < NN) rowptr[idx] = tb + loc[i];
    }
    if (t == 0) rowptr[NN] = NE;
}

// ---------------------------------------------------------------------------
// p0 (layer 0, no fold): p[n][m] = x[n,:] @ U0[m,:]  (x fp32)
// ---------------------------------------------------------------------------
__device__ __forceinline__ void dev_pk0(const float* __restrict__ h,
                                        const float* __restrict__ U,
                                        float* __restrict__ pout, int vb) {
    __shared__ float usc_s[4][64];
    int t = threadIdx.x;
    {
        int m = t >> 6, k = t & 63;
        usc_s[m][k] = U[m * 64 + k];
    }
    __syncthreads();
    int idx = vb * 256 + t;
    if (idx < NN * 4) {
        int n = idx >> 2, m = idx & 3;
        const float4* hn = reinterpret_cast<const float4*>(h) + (size_t)n * 16;
        const float* um = usc_s[m];
        float a = 0.0f;
#pragma unroll
        for (int j = 0; j < 16; ++j) {
            float4 hv = hn[j];
            a += hv.x * um[4 * j + 0] + hv.y * um[4 * j + 1] +
                 hv.z * um[4 * j + 2] + hv.w * um[4 * j + 3];
        }
        pout[idx] = a;
    }
}

// ---------------------------------------------------------------------------
// Fused: blocks 0..1874 scatter CSR (cursor-free: atomicSub on degi, which is
// dead after scan; fill order within a row is irrelevant); blocks 1875..
// compute p0 = x@U0^T.
// ---------------------------------------------------------------------------
__global__ __launch_bounds__(256) void k_scatter_pk0(const void* __restrict__ ei,
                                                     const int* __restrict__ rowptr,
                                                     int* __restrict__ degi,
                                                     int* __restrict__ csr,
                                                     const float* __restrict__ x,
                                                     const float* __restrict__ U0,
                                                     float* __restrict__ p) {
    if (blockIdx.x < EBLK) {
        int is64 = detect64((const unsigned int*)ei);
        int e = blockIdx.x * 256 + threadIdx.x;
        int s = load_idx(ei, is64, e);
        int d = load_idx(ei, is64, NE + e);
        int old = atomicSub(&degi[d], 1);
        csr[rowptr[d] + old - 1] = s;
    } else {
        dev_pk0(x, U0, p, blockIdx.x - EBLK);
    }
}

// ---------------------------------------------------------------------------
// k_pk (fold layers): sums stats shards -> sc/sh; writes scv + cstv (block 0)
// and p[n][m] = hbf[n,:] @ (U[m,:]*sc).  Reads bf16 features directly
// (fp32 h array deleted — p is now computed from the same bf16 features the
// aggregation consumes; within 0.5 abs tolerance).
// ---------------------------------------------------------------------------
__global__ __launch_bounds__(256) void k_pk(const ushort* __restrict__ hbf,
                                            const float* __restrict__ U,
                                            const float* __restrict__ statsS,
                                            const float* __restrict__ g,
                                            const float* __restrict__ W,
                                            const float* __restrict__ bt,
                                            float* __restrict__ pout,
                                            float* __restrict__ cstv_out,
                                            float* __restrict__ scv_out) {
    __shared__ float usc_s[4][64];
    __shared__ float sc_l[64];
    __shared__ float sh_l[64];
    int t = threadIdx.x;
    if (t < 64) {
        float s1 = 0.0f, s2 = 0.0f;
#pragma unroll
        for (int sh = 0; sh < NSHARD; ++sh) {
            s1 += statsS[sh * 128 + t];
            s2 += statsS[sh * 128 + 64 + t];
        }
        const float invN = 1.0f / (float)NN;
        float mu = s1 * invN;
        float var = s2 * invN - mu * mu;
        float sc = rsqrtf(var + BN_EPS) * g[t];
        sc_l[t] = sc;
        sh_l[t] = bt[t] - mu * sc;
        if (blockIdx.x == 0) scv_out[t] = sc;
    }
    __syncthreads();
    {
        int m = t >> 6, k = t & 63;
        usc_s[m][k] = U[m * 64 + k] * sc_l[k];
    }
    __syncthreads();
    int idx = blockIdx.x * 256 + t;
    if (idx < NN * 4) {
        int n = idx >> 2, m = idx & 3;
        const uint4* hn = reinterpret_cast<const uint4*>(hbf + (size_t)n * 64);
        const float* um = usc_s[m];
        float a = 0.0f;
#pragma unroll
        for (int j = 0; j < 8; ++j) {
            uint4 v = hn[j];
            a += bf2f((unsigned short)v.x) * um[8 * j + 0] +
                 bf2f((unsigned short)(v.x >> 16)) * um[8 * j + 1] +
                 bf2f((unsigned short)v.y) * um[8 * j + 2] +
                 bf2f((unsigned short)(v.y >> 16)) * um[8 * j + 3] +
                 bf2f((unsigned short)v.z) * um[8 * j + 4] +
                 bf2f((unsigned short)(v.z >> 16)) * um[8 * j + 5] +
                 bf2f((unsigned short)v.w) * um[8 * j + 6] +
                 bf2f((unsigned short)(v.w >> 16)) * um[8 * j + 7];
        }
        pout[idx] = a;
    }
    if (blockIdx.x == 0) {
        float s = 0.0f;
        const float* wr = W + (size_t)t * 64;
#pragma unroll 8
        for (int k = 0; k < 64; ++k) s += sh_l[k] * wr[k];
        cstv_out[t] = s;
    }
}

// ---------------------------------------------------------------------------
// Fused aggregate + GEMM, 8-wave gang (R9-verified structure). 512 thr =
// 8 waves = 8 nodes/block, 4 gangs/CU. Phase A: wave per node, lane =
// channel; gather-aggregate, scale by invD*sc, bf16 z row -> LDS + zs.
// ONE barrier. Phase B: waves 0..3 one 16-col o-tile each over 8 nodes
// (A rows 8..15 clamped/discarded); waves 4..7 exit. STATS layers store
// bf16 features only (fp32 h deleted); final layer stores fp32 d_out.
// ---------------------------------------------------------------------------
template <int FOLD, int STATS>
__global__ __launch_bounds__(512, 4) void k_fused(const int* __restrict__ rowptr,
                                                  const int* __restrict__ csr,
                                                  const float* __restrict__ p,
                                                  const ushort* __restrict__ hbf_in,
                                                  const float* __restrict__ cvec,
                                                  const float* __restrict__ scv,
                                                  const float* __restrict__ cstvg,
                                                  const ushort* __restrict__ wb,
                                                  const float* __restrict__ bvec,
                                                  float* __restrict__ hout,
                                                  ushort* __restrict__ hbfout,
                                                  float* __restrict__ stats_out) {
    __shared__ float4 attn_s[8][64];
    __shared__ int src_s[8][64];
    __shared__ ushort zrow[8][272];   // 544B stride: 16B-aligned rows
    __shared__ float4 zs_s[8];
    __shared__ float cstv_s[256];

    int t = threadIdx.x;
    int wid = t >> 6;
    int lane = t & 63;
    int n = blockIdx.x * 8 + wid;
    const float4* p4 = reinterpret_cast<const float4*>(p);

    if (FOLD && t < 256) cstv_s[t] = cstvg[t];

    float scl = FOLD ? scv[lane] : 1.0f;

    float4 cv = make_float4(cvec[0], cvec[1], cvec[2], cvec[3]);
    float smx = fmaxf(fmaxf(cv.x, cv.y), fmaxf(cv.z, cv.w));
    float se0 = __expf(cv.x - smx), se1 = __expf(cv.y - smx);
    float se2 = __expf(cv.z - smx), se3 = __expf(cv.w - smx);
    float sinv = 1.0f / (se0 + se1 + se2 + se3);
    float sl0 = se0 * sinv, sl1 = se1 * sinv, sl2 = se2 * sinv, sl3 = se3 * sinv;

    float4 pd = p4[n];
    float4 pdc = make_float4(pd.x + cv.x, pd.y + cv.y, pd.z + cv.z, pd.w + cv.w);
    float hs = bf2f(hbf_in[(unsigned)(n * 64 + lane)]);
    float acc0 = sl0 * hs, acc1 = sl1 * hs, acc2 = sl2 * hs, acc3 = sl3 * hs;
    float zt0 = sl0, zt1 = sl1, zt2 = sl2, zt3 = sl3;

    int start = rowptr[n];
    int end = rowptr[n + 1];
    for (int j = start; j < end; j += 64) {
        int chunk = end - j;
        if (chunk > 64) chunk = 64;
        if (lane < chunk) {
            int s = csr[j + lane];
            float4 q = p4[(unsigned)s];
            float l0 = pdc.x - q.x;
            float l1 = pdc.y - q.y;
            float l2 = pdc.z - q.z;
            float l3 = pdc.w - q.w;
            float mx = fmaxf(fmaxf(l0, l1), fmaxf(l2, l3));  // REQUIRED (R5 NaN)
            float e0 = __expf(l0 - mx);
            float e1 = __expf(l1 - mx);
            float e2 = __expf(l2 - mx);
            float e3 = __expf(l3 - mx);
            float inv = 1.0f / (e0 + e1 + e2 + e3);
            attn_s[wid][lane] = make_float4(e0 * inv, e1 * inv, e2 * inv, e3 * inv);
            src_s[wid][lane] = s;
        }
        int k = 0;
        for (; k + 4 <= chunk; k += 4) {
            float4 a0 = attn_s[wid][k];
            int s0 = src_s[wid][k];
            float4 a1 = attn_s[wid][k + 1];
            int s1 = src_s[wid][k + 1];
            float4 a2 = attn_s[wid][k + 2];
            int s2 = src_s[wid][k + 2];
            float4 a3 = attn_s[wid][k + 3];
            int s3 = src_s[wid][k + 3];
            float h0 = bf2f(hbf_in[(unsigned)(s0 * 64 + lane)]);
            float h1 = bf2f(hbf_in[(unsigned)(s1 * 64 + lane)]);
            float h2 = bf2f(hbf_in[(unsigned)(s2 * 64 + lane)]);
            float h3 = bf2f(hbf_in[(unsigned)(s3 * 64 + lane)]);
            acc0 += a0.x * h0 + a1.x * h1 + a2.x * h2 + a3.x * h3;
            acc1 += a0.y * h0 + a1.y * h1 + a2.y * h2 + a3.y * h3;
            acc2 += a0.z * h0 + a1.z * h1 + a2.z * h2 + a3.z * h3;
            acc3 += a0.w * h0 + a1.w * h1 + a2.w * h2 + a3.w * h3;
            zt0 += a0.x + a1.x + a2.x + a3.x;
            zt1 += a0.y + a1.y + a2.y + a3.y;
            zt2 += a0.z + a1.z + a2.z + a3.z;
            zt3 += a0.w + a1.w + a2.w + a3.w;
        }
        for (; k < chunk; ++k) {
            float4 a0 = attn_s[wid][k];
            int s0 = src_s[wid][k];
            float h0 = bf2f(hbf_in[(unsigned)(s0 * 64 + lane)]);
            acc0 += a0.x * h0;
            acc1 += a0.y * h0;
            acc2 += a0.z * h0;
            acc3 += a0.w * h0;
            zt0 += a0.x; zt1 += a0.y; zt2 += a0.z; zt3 += a0.w;
        }
    }

    float invD = 1.0f / (float)(end - start + 1);
    float s = invD * scl;
    {
        ushort* zr = &zrow[wid][0];
        zr[lane]       = f2bf(acc0 * s);
        zr[64 + lane]  = f2bf(acc1 * s);
        zr[128 + lane] = f2bf(acc2 * s);
        zr[192 + lane] = f2bf(acc3 * s);
        if (lane == 0)
            zs_s[wid] = make_float4(zt0 * invD, zt1 * invD, zt2 * invD, zt3 * invD);
    }
    __syncthreads();

    // ---- phase B: waves 0..3, one o-tile each; waves 4..7 done ----
    if (wid >= 4) return;

    int col = lane & 15;
    int grp = lane >> 4;
    int r = (col < 8) ? col : 7;        // A rows 8..15 clamped (discarded)
    const ushort* zr = &zrow[r][0];
    const ushort* wbp = wb + ((size_t)(wid * 8) * 64 + lane) * 8;
    f32x4 acc = {0.0f, 0.0f, 0.0f, 0.0f};
#pragma unroll
    for (int kb = 0; kb < 8; ++kb) {
        bf16x8 a = *reinterpret_cast<const bf16x8*>(zr + kb * 32 + grp * 8);
        bf16x8 b = *reinterpret_cast<const bf16x8*>(wbp + (size_t)kb * 512);
        acc = __builtin_amdgcn_mfma_f32_16x16x32_bf16(a, b, acc, 0, 0, 0);
    }

    // D layout: row=(lane>>4)*4+i, col=lane&15. Valid rows 0..7 -> grp<2.
    float ls = 0.0f, lq = 0.0f;
    if (grp < 2) {
        int n0 = blockIdx.x * 8;
        int o = wid * 16 + col;
        float bval = bvec[o];
#pragma unroll
        for (int i = 0; i < 4; ++i) {
            int nn = n0 + grp * 4 + i;
            float v = acc[i] + bval;
            if (FOLD) {
                float4 zv = zs_s[grp * 4 + i];
                v += zv.x * cstv_s[o] + zv.y * cstv_s[64 + o] +
                     zv.z * cstv_s[128 + o] + zv.w * cstv_s[192 + o];
            }
            if (STATS) {
                v = fmaxf(v, 0.0f);
                hbfout[(size_t)nn * 64 + o] = f2bf(v);  // bf16 only (h deleted)
                ls += v;
                lq += v * v;
            } else {
                hout[(size_t)nn * 64 + o] = v;          // final layer: fp32 out
            }
        }
        if (STATS) {
            // fold grp1 (rows 4..7) into grp0 (rows 0..3)
            ls += __shfl_xor(ls, 16, 64);
            lq += __shfl_xor(lq, 16, 64);
            if (lane < 16) {
                float* so = stats_out + (blockIdx.x & (NSHARD - 1)) * 128;
                atomicAdd(&so[o], ls);
                atomicAdd(&so[64 + o], lq);
            }
        }
    }
}

extern "C" void kernel_launch(void* const* d_in, const int* in_sizes, int n_in,
                              void* d_out, int out_size, void* d_ws, size_t ws_size,
                              hipStream_t stream) {
    const float* x = (const float*)d_in[0];
    const void* ei = d_in[1];
    const float* W0 = (const float*)d_in[2];
    const float* U0 = (const float*)d_in[3];
    const float* c0 = (const float*)d_in[4];
    const float* b0 = (const float*)d_in[5];
    const float* g0 = (const float*)d_in[6];
    const float* bt0 = (const float*)d_in[7];
    const float* W1 = (const float*)d_in[8];
    const float* U1 = (const float*)d_in[9];
    const float* c1 = (const float*)d_in[10];
    const float* b1 = (const float*)d_in[11];
    const float* g1 = (const float*)d_in[12];
    const float* bt1 = (const float*)d_in[13];
    const float* W2 = (const float*)d_in[14];
    const float* U2 = (const float*)d_in[15];
    const float* c2 = (const float*)d_in[16];
    const float* b2 = (const float*)d_in[17];

    // workspace layout — all 16B-aligned; fp32 h and cursor arrays deleted
    ushort* xbf = (ushort*)d_ws;                      // NN*64 bf16
    ushort* hbfA = xbf + (size_t)NN * 64;             // NN*64 (double buffer A)
    ushort* hbfB = hbfA + (size_t)NN * 64;            // NN*64 (double buffer B)
    float* p = (float*)(hbfB + (size_t)NN * 64);      // NN*4
    float* cstv = p + (size_t)NN * 4;                 // 256
    float* scv = cstv + 256;                          // 64
    int* degi = (int*)(scv + 64);                     // NN (memset-zeroed)
    float* statsA = (float*)(degi + NN);              // 2*16*128 = 4096
    int* rowptr = (int*)(statsA + 4096);              // NN+4
    int* csr = rowptr + NN + 4;                       // NE
    ushort* wb = (ushort*)(csr + NE);                 // 3*16384 bf16
    float* stats0 = statsA;
    float* stats1 = statsA + 2048;

    // 9 stream ops (memset + 8 kernels)
    hipMemsetAsync(degi, 0, sizeof(int) * NN, stream);
    k_prep_hist<<<3946, 256, 0, stream>>>(x, W0, W1, W2, ei, xbf, wb,
                                          (int4*)statsA, degi);
    k_scan<<<1, 1024, 0, stream>>>(degi, rowptr);
    k_scatter_pk0<<<EBLK + PKBLK, 256, 0, stream>>>(ei, rowptr, degi, csr,
                                                    x, U0, p);

    // ---- layer 0: read xbf, write hbfA + stats0 shards ----
    k_fused<0, 1><<<FBLK, 512, 0, stream>>>(rowptr, csr, p, xbf, c0,
                                            nullptr, nullptr, wb, b0,
                                            nullptr, hbfA, stats0);
    // ---- layer 1: fold BN0; read hbfA, write hbfB + stats1 shards ----
    k_pk<<<PKBLK, 256, 0, stream>>>(hbfA, U1, stats0, g0, W1, bt0, p, cstv, scv);
    k_fused<1, 1><<<FBLK, 512, 0, stream>>>(rowptr, csr, p, hbfA, c1,
                                            scv, cstv, wb + 16384, b1,
                                            nullptr, hbfB, stats1);
    // ---- layer 2: fold BN1; read hbfB, write d_out (fp32) ----
    k_pk<<<PKBLK, 256, 0, stream>>>(hbfB, U2, stats1, g1, W2, bt1, p, cstv, scv);
    k_fused<1, 0><<<FBLK, 512, 0, stream>>>(rowptr, csr, p, hbfB, c2,
                                            scv, cstv, wb + 32768, b2,
                                            (float*)d_out, nullptr, nullptr);
}